// Round 1
// baseline (442.383 us; speedup 1.0000x reference)
//
#include <hip/hip_runtime.h>
#include <stdint.h>

typedef __bf16 bf16;
typedef __bf16 bf16x4 __attribute__((ext_vector_type(4)));
typedef __bf16 bf16x8 __attribute__((ext_vector_type(8)));
typedef float  f32x4  __attribute__((ext_vector_type(4)));

#define DMODEL 2048
#define NH 16
#define DK 128
#define SS 1024
#define PASTLEN 3072
#define LTOT 4096
#define MTOT 2048

// ---- async global->LDS, 16B per lane (HW: wave-uniform LDS base + lane*16) ----
__device__ __forceinline__ void gload16(const void* g, void* l) {
    __builtin_amdgcn_global_load_lds(
        (__attribute__((address_space(1))) void*)(uintptr_t)g,
        (__attribute__((address_space(3))) void*)(uintptr_t)l,
        16, 0, 0);
}

// ---- fp32 -> bf16 convert, 5 equal-size tensors selected by blockIdx.y ----
__global__ __launch_bounds__(256) void cvt5_k(
    const float* __restrict__ s0, const float* __restrict__ s1,
    const float* __restrict__ s2, const float* __restrict__ s3,
    const float* __restrict__ s4,
    bf16* __restrict__ d0, bf16* __restrict__ d1, bf16* __restrict__ d2,
    bf16* __restrict__ d3, bf16* __restrict__ d4, int n8)
{
    const float* s; bf16* d;
    switch (blockIdx.y) {
        case 0: s = s0; d = d0; break;
        case 1: s = s1; d = d1; break;
        case 2: s = s2; d = d2; break;
        case 3: s = s3; d = d3; break;
        default: s = s4; d = d4; break;
    }
    int stride = gridDim.x * blockDim.x;
    for (int i = blockIdx.x*blockDim.x + threadIdx.x; i < n8; i += stride) {
        const float4* p = (const float4*)s + (size_t)i*2;
        float4 a = p[0], b = p[1];
        bf16x8 o;
        o[0]=(bf16)a.x; o[1]=(bf16)a.y; o[2]=(bf16)a.z; o[3]=(bf16)a.w;
        o[4]=(bf16)b.x; o[5]=(bf16)b.y; o[6]=(bf16)b.z; o[7]=(bf16)b.w;
        *((bf16x8*)d + i) = o;
    }
}

// ---- copy past K/V [B,H,3072,128] into d_out [B,H,4096,128] rows 0..3072 ----
__global__ __launch_bounds__(256) void copy_past_k(
    const float* __restrict__ src, float* __restrict__ dst, int n4)
{
    const int per_bh = PASTLEN*DK/4;   // 98304 float4 per (b,h)
    const int dst_bh = LTOT*DK/4;      // 131072
    int stride = gridDim.x * blockDim.x;
    for (int i = blockIdx.x*blockDim.x + threadIdx.x; i < n4; i += stride) {
        int bh = i / per_bh;
        int r  = i - bh*per_bh;
        ((float4*)dst)[(size_t)bh*dst_bh + r] = ((const float4*)src)[i];
    }
}

// ---- Y = A(bf16 MxK) @ W^T (W: NxK bf16) + bias ; 128x128 tile, BK=32 ----
// mode 0: fused QKV (blockIdx.y: which = y>>4, ntile = y&15), epilogue scatters
// mode 1: out-projection, fp32 [M][N] row-major to outO
__global__ __launch_bounds__(256) void gemm_bt(
    const bf16* __restrict__ A,
    const bf16* __restrict__ W0, const bf16* __restrict__ W1, const bf16* __restrict__ W2,
    const float* __restrict__ b0, const float* __restrict__ b1, const float* __restrict__ b2,
    bf16* __restrict__ outQ, float* __restrict__ outK, float* __restrict__ outV,
    float* __restrict__ outO, int mode)
{
    __shared__ __align__(16) bf16 As[128*32];
    __shared__ __align__(16) bf16 Bs[128*32];
    const int tid  = threadIdx.x;
    const int wave = tid >> 6, lane = tid & 63;
    const int l15 = lane & 15, l4 = lane >> 4;
    int which, ntile;
    if (mode == 0) { which = blockIdx.y >> 4; ntile = blockIdx.y & 15; }
    else           { which = 3;               ntile = blockIdx.y; }
    const bf16*  W    = (mode != 0 || which == 0) ? W0 : (which == 1 ? W1 : W2);
    const float* bias = (mode != 0 || which == 0) ? b0 : (which == 1 ? b1 : b2);
    const int m0 = blockIdx.x * 128, n0 = ntile * 128;
    const int wm = wave >> 1, wn = wave & 1;

    f32x4 acc[4][4] = {};

    for (int k0 = 0; k0 < DMODEL; k0 += 32) {
        __syncthreads();
        #pragma unroll
        for (int c = 0; c < 2; ++c) {
            const int base = c*4096 + wave*1024;      // wave-uniform LDS byte base
            const int byte = base + lane*16;          // this lane's dest
            const int row  = byte >> 6;               // 64B per 32-elem bf16 row
            const int ke   = (byte & 63) >> 1;        // k-element within row
            gload16(A + (size_t)(m0+row)*DMODEL + k0 + ke, (char*)As + base);
            gload16(W + (size_t)(n0+row)*DMODEL + k0 + ke, (char*)Bs + base);
        }
        asm volatile("s_waitcnt vmcnt(0)" ::: "memory");
        __syncthreads();
        bf16x8 af[4], bfv[4];
        #pragma unroll
        for (int mf = 0; mf < 4; ++mf)
            af[mf] = *(const bf16x8*)((const char*)As + (wm*64 + mf*16 + l15)*64 + l4*16);
        #pragma unroll
        for (int nf = 0; nf < 4; ++nf)
            bfv[nf] = *(const bf16x8*)((const char*)Bs + (wn*64 + nf*16 + l15)*64 + l4*16);
        #pragma unroll
        for (int mf = 0; mf < 4; ++mf)
            #pragma unroll
            for (int nf = 0; nf < 4; ++nf)
                acc[mf][nf] = __builtin_amdgcn_mfma_f32_16x16x32_bf16(af[mf], bfv[nf], acc[mf][nf], 0, 0, 0);
    }

    float bv4[4];
    #pragma unroll
    for (int nf = 0; nf < 4; ++nf) bv4[nf] = bias[n0 + wn*64 + nf*16 + l15];

    const int rbase = m0 + wm*64 + l4*4;
    const int cbase = n0 + wn*64 + l15;

    if (mode == 1) {
        #pragma unroll
        for (int mf = 0; mf < 4; ++mf)
        #pragma unroll
        for (int nf = 0; nf < 4; ++nf) {
            const int col = cbase + nf*16;
            #pragma unroll
            for (int r = 0; r < 4; ++r) {
                const int row = rbase + mf*16 + r;
                outO[(size_t)row*DMODEL + col] = acc[mf][nf][r] + bv4[nf];
            }
        }
    } else if (which == 0) {
        // Q: fold 1/sqrt(dk) * log2(e) so attention can use exp2 directly
        const float qs = 0.08838834764831845f * 1.4426950408889634f;
        #pragma unroll
        for (int mf = 0; mf < 4; ++mf)
        #pragma unroll
        for (int nf = 0; nf < 4; ++nf) {
            const int col = cbase + nf*16;
            const int h = col >> 7, d = col & 127;
            #pragma unroll
            for (int r = 0; r < 4; ++r) {
                const int row = rbase + mf*16 + r;
                const int b = row >> 10, s = row & 1023;
                outQ[((size_t)(b*NH + h)*SS + s)*DK + d] = (bf16)((acc[mf][nf][r] + bv4[nf]) * qs);
            }
        }
    } else {
        float* dst = (which == 1) ? outK : outV;
        #pragma unroll
        for (int mf = 0; mf < 4; ++mf)
        #pragma unroll
        for (int nf = 0; nf < 4; ++nf) {
            const int col = cbase + nf*16;
            const int h = col >> 7, d = col & 127;
            #pragma unroll
            for (int r = 0; r < 4; ++r) {
                const int row = rbase + mf*16 + r;
                const int b = row >> 10, s = row & 1023;
                dst[((size_t)(b*NH + h)*LTOT + PASTLEN + s)*DK + d] = acc[mf][nf][r] + bv4[nf];
            }
        }
    }
}

// ---- flash attention: 4 waves, 128 queries/block (2 x 64 sub-tiles), KV tile 64 ----
__global__ __launch_bounds__(256) void attn_k(
    const bf16* __restrict__ Qb,      // [B,H,S,DK], pre-scaled by 1/sqrt(dk)*log2e
    const float* __restrict__ Kg,     // d_out K region [B,H,LTOT,DK] fp32
    const float* __restrict__ Vg,     // d_out V region
    bf16* __restrict__ Ob)            // [B*S][DMODEL], col = h*128+d
{
    __shared__ __align__(16) bf16 Ks[64*128];     // row-swizzled: byte ^= (row&7)<<4
    __shared__ __align__(16) bf16 Vt[128*64];     // V^T, chunk-swizzled
    __shared__ __align__(16) bf16 Ps[4][16*72];   // per-wave P transpose buffer (72 = 64+8 pad)

    const int tid  = threadIdx.x;
    const int wave = tid >> 6, lane = tid & 63;
    const int l15 = lane & 15, l4 = lane >> 4;
    const int qt = blockIdx.x;       // 0..7  (128 queries each)
    const int bh = blockIdx.y;       // 0..31
    const int b = bh >> 4, h = bh & 15;

    // Q fragments in registers: wave owns rows [wave*16, wave*16+16) of each sub-tile
    bf16x8 qf[2][4];
    #pragma unroll
    for (int qq = 0; qq < 2; ++qq) {
        const bf16* qbase = Qb + ((size_t)bh*SS + qt*128 + qq*64 + wave*16 + l15)*DK;
        #pragma unroll
        for (int ks = 0; ks < 4; ++ks)
            qf[qq][ks] = *(const bf16x8*)(qbase + ks*32 + l4*8);
    }

    const float* Kbh = Kg + (size_t)bh*LTOT*DK;
    const float* Vbh = Vg + (size_t)bh*LTOT*DK;

    float m_run[2][4], l_run[2][4];
    f32x4 oacc[2][8];
    #pragma unroll
    for (int qq = 0; qq < 2; ++qq) {
        #pragma unroll
        for (int r = 0; r < 4; ++r) { m_run[qq][r] = -1e30f; l_run[qq][r] = 0.f; }
        #pragma unroll
        for (int df = 0; df < 8; ++df) oacc[qq][df] = f32x4{0.f, 0.f, 0.f, 0.f};
    }

    for (int t = 0; t < LTOT/64; ++t) {
        // ---- stage K (swizzled) and V^T (swizzled) tiles, fp32 -> bf16 ----
        const float4* Ksrc = (const float4*)(Kbh + (size_t)t*64*DK);
        const float4* Vsrc = (const float4*)(Vbh + (size_t)t*64*DK);
        #pragma unroll
        for (int i = 0; i < 8; ++i) {
            const int f4  = i*256 + tid;       // 0..2047
            const int row = f4 >> 5;           // kv row 0..63
            const int c4  = (f4 & 31) << 2;    // d col (multiple of 4)
            float4 kv4 = Ksrc[f4];
            bf16x4 kb;
            kb[0]=(bf16)kv4.x; kb[1]=(bf16)kv4.y; kb[2]=(bf16)kv4.z; kb[3]=(bf16)kv4.w;
            *(bf16x4*)((char*)Ks + ((row*256 + c4*2) ^ ((row&7)<<4))) = kb;
            float4 vv4 = Vsrc[f4];
            float vs[4] = {vv4.x, vv4.y, vv4.z, vv4.w};
            #pragma unroll
            for (int jj = 0; jj < 4; ++jj) {
                const int d  = c4 + jj;
                const int pc = (row>>3) ^ ((d ^ (d>>2)) & 7);   // 16B chunk swizzle
                *(bf16*)((char*)Vt + d*128 + pc*16 + (row&7)*2) = (bf16)vs[jj];
            }
        }
        __syncthreads();

        #pragma unroll
        for (int qq = 0; qq < 2; ++qq) {
            // ---- S = Q K^T (in log2e units already) ----
            f32x4 sa[4] = {};
            #pragma unroll
            for (int nf = 0; nf < 4; ++nf) {
                const int krow = nf*16 + l15;
                #pragma unroll
                for (int ks = 0; ks < 4; ++ks) {
                    bf16x8 kf = *(const bf16x8*)((const char*)Ks +
                        krow*256 + ((ks*64 + l4*16) ^ ((krow&7)<<4)));
                    sa[nf] = __builtin_amdgcn_mfma_f32_16x16x32_bf16(qf[qq][ks], kf, sa[nf], 0, 0, 0);
                }
            }
            // ---- online softmax: rows r live in 16-lane groups sharing l4 ----
            #pragma unroll
            for (int r = 0; r < 4; ++r) {
                float mt = fmaxf(fmaxf(sa[0][r], sa[1][r]), fmaxf(sa[2][r], sa[3][r]));
                #pragma unroll
                for (int off = 1; off < 16; off <<= 1) mt = fmaxf(mt, __shfl_xor(mt, off, 64));
                const float mn   = fmaxf(m_run[qq][r], mt);
                const float corr = exp2f(m_run[qq][r] - mn);
                m_run[qq][r] = mn;
                float sum = 0.f;
                #pragma unroll
                for (int nf = 0; nf < 4; ++nf) {
                    float p = exp2f(sa[nf][r] - mn);
                    sa[nf][r] = p;
                    sum += p;
                }
                #pragma unroll
                for (int off = 1; off < 16; off <<= 1) sum += __shfl_xor(sum, off, 64);
                l_run[qq][r] = l_run[qq][r]*corr + sum;
                #pragma unroll
                for (int df = 0; df < 8; ++df) oacc[qq][df][r] *= corr;
            }
            // ---- P -> per-wave LDS (transpose C-layout -> A-layout) ----
            #pragma unroll
            for (int nf = 0; nf < 4; ++nf)
                #pragma unroll
                for (int r = 0; r < 4; ++r)
                    Ps[wave][(l4*4 + r)*72 + nf*16 + l15] = (bf16)sa[nf][r];
            // ---- O += P V ----
            #pragma unroll
            for (int ks2 = 0; ks2 < 2; ++ks2) {
                bf16x8 pf = *(const bf16x8*)((const char*)&Ps[wave][0] + l15*144 + ks2*64 + l4*16);
                #pragma unroll
                for (int df = 0; df < 8; ++df) {
                    const int d  = df*16 + l15;
                    const int pc = ((ks2*4 + l4) ^ ((d ^ (d>>2)) & 7));
                    bf16x8 vf = *(const bf16x8*)((const char*)Vt + d*128 + pc*16);
                    oacc[qq][df] = __builtin_amdgcn_mfma_f32_16x16x32_bf16(pf, vf, oacc[qq][df], 0, 0, 0);
                }
            }
        }
        __syncthreads();
    }

    // ---- normalize and write O as bf16 [B*S][H*DK] ----
    #pragma unroll
    for (int qq = 0; qq < 2; ++qq) {
        float inv[4];
        #pragma unroll
        for (int r = 0; r < 4; ++r) inv[r] = 1.f / l_run[qq][r];
        const int mbase = b*SS + qt*128 + qq*64 + wave*16 + l4*4;
        #pragma unroll
        for (int df = 0; df < 8; ++df) {
            const int col = h*128 + df*16 + l15;
            #pragma unroll
            for (int r = 0; r < 4; ++r)
                Ob[(size_t)(mbase + r)*DMODEL + col] = (bf16)(oacc[qq][df][r]*inv[r]);
        }
    }
}

extern "C" void kernel_launch(void* const* d_in, const int* in_sizes, int n_in,
                              void* d_out, int out_size, void* d_ws, size_t ws_size,
                              hipStream_t stream) {
    const float* x  = (const float*)d_in[0];
    const float* pk = (const float*)d_in[1];
    const float* pv = (const float*)d_in[2];
    const float* Wq = (const float*)d_in[3];
    const float* bq = (const float*)d_in[4];
    const float* Wk = (const float*)d_in[5];
    const float* bk = (const float*)d_in[6];
    const float* Wv = (const float*)d_in[7];
    const float* bv = (const float*)d_in[8];
    const float* Wo = (const float*)d_in[9];
    const float* bo = (const float*)d_in[10];

    float* out  = (float*)d_out;                 // [B,S,DMODEL]
    float* Kout = out + 4194304;                 // [B,H,4096,128]
    float* Vout = out + 20971520;

    char* ws = (char*)d_ws;
    bf16* xb  = (bf16*)(ws);
    bf16* Wqb = (bf16*)(ws + 8388608);
    bf16* Wkb = (bf16*)(ws + 16777216);
    bf16* Wvb = (bf16*)(ws + 25165824);
    bf16* Wob = (bf16*)(ws + 33554432);
    bf16* Qb  = (bf16*)(ws + 41943040);          // [B,H,S,DK] bf16, pre-scaled
    bf16* Ob  = (bf16*)(ws + 50331648);          // [B*S][DMODEL] bf16

    // 1) fp32 -> bf16 converts (x + 4 weights, each 2048*2048 elements)
    cvt5_k<<<dim3(1024, 5), 256, 0, stream>>>(x, Wq, Wk, Wv, Wo,
                                              xb, Wqb, Wkb, Wvb, Wob, 524288);
    // 2) past K/V -> d_out cache regions
    copy_past_k<<<2048, 256, 0, stream>>>(pk, Kout, 3145728);
    copy_past_k<<<2048, 256, 0, stream>>>(pv, Vout, 3145728);
    // 3) fused QKV projection
    gemm_bt<<<dim3(16, 48), 256, 0, stream>>>(xb, Wqb, Wkb, Wvb, bq, bk, bv,
                                              Qb, Kout, Vout, nullptr, 0);
    // 4) flash attention
    attn_k<<<dim3(8, 32), 256, 0, stream>>>(Qb, Kout, Vout, Ob);
    // 5) output projection
    gemm_bt<<<dim3(16, 16), 256, 0, stream>>>(Ob, Wob, nullptr, nullptr, bo, nullptr, nullptr,
                                              nullptr, nullptr, nullptr, out, 1);
}

// Round 2
// 337.149 us; speedup vs baseline: 1.3121x; 1.3121x over previous
//
#include <hip/hip_runtime.h>
#include <stdint.h>

typedef __bf16 bf16;
typedef __bf16 bf16x4 __attribute__((ext_vector_type(4)));
typedef __bf16 bf16x8 __attribute__((ext_vector_type(8)));
typedef float  f32x4  __attribute__((ext_vector_type(4)));

#define DMODEL 2048
#define NH 16
#define DK 128
#define SS 1024
#define PASTLEN 3072
#define LTOT 4096
#define KVTILES 64
#define NSPLIT 2
#define NT 32

// ---- async global->LDS, 16B per lane (wave-uniform LDS base + lane*16) ----
__device__ __forceinline__ void gload16(const void* g, void* l) {
    __builtin_amdgcn_global_load_lds(
        (__attribute__((address_space(1))) void*)(uintptr_t)g,
        (__attribute__((address_space(3))) void*)(uintptr_t)l,
        16, 0, 0);
}

// ---- fp32 -> bf16 convert, 5 equal-size tensors selected by blockIdx.y ----
__global__ __launch_bounds__(256) void cvt5_k(
    const float* __restrict__ s0, const float* __restrict__ s1,
    const float* __restrict__ s2, const float* __restrict__ s3,
    const float* __restrict__ s4,
    bf16* __restrict__ d0, bf16* __restrict__ d1, bf16* __restrict__ d2,
    bf16* __restrict__ d3, bf16* __restrict__ d4, int n8)
{
    const float* s; bf16* d;
    switch (blockIdx.y) {
        case 0: s = s0; d = d0; break;
        case 1: s = s1; d = d1; break;
        case 2: s = s2; d = d2; break;
        case 3: s = s3; d = d3; break;
        default: s = s4; d = d4; break;
    }
    int stride = gridDim.x * blockDim.x;
    for (int i = blockIdx.x*blockDim.x + threadIdx.x; i < n8; i += stride) {
        const float4* p = (const float4*)s + (size_t)i*2;
        float4 a = p[0], b = p[1];
        bf16x8 o;
        o[0]=(bf16)a.x; o[1]=(bf16)a.y; o[2]=(bf16)a.z; o[3]=(bf16)a.w;
        o[4]=(bf16)b.x; o[5]=(bf16)b.y; o[6]=(bf16)b.z; o[7]=(bf16)b.w;
        *((bf16x8*)d + i) = o;
    }
}

// ---- Y = A(bf16 MxK) @ W^T + bias ; 128x128 tile, BK=32 (m97 structure) ----
__global__ __launch_bounds__(256) void gemm_bt(
    const bf16* __restrict__ A,
    const bf16* __restrict__ W0, const bf16* __restrict__ W1, const bf16* __restrict__ W2,
    const float* __restrict__ b0, const float* __restrict__ b1, const float* __restrict__ b2,
    bf16* __restrict__ outQ, float* __restrict__ outK, float* __restrict__ outV,
    float* __restrict__ outO, int mode)
{
    __shared__ __align__(16) bf16 As[128*32];
    __shared__ __align__(16) bf16 Bs[128*32];
    const int tid  = threadIdx.x;
    const int wave = tid >> 6, lane = tid & 63;
    const int l15 = lane & 15, l4 = lane >> 4;
    int which, ntile;
    if (mode == 0) { which = blockIdx.y >> 4; ntile = blockIdx.y & 15; }
    else           { which = 3;               ntile = blockIdx.y; }
    const bf16*  W    = (mode != 0 || which == 0) ? W0 : (which == 1 ? W1 : W2);
    const float* bias = (mode != 0 || which == 0) ? b0 : (which == 1 ? b1 : b2);
    const int m0 = blockIdx.x * 128, n0 = ntile * 128;
    const int wm = wave >> 1, wn = wave & 1;

    f32x4 acc[4][4] = {};

    for (int k0 = 0; k0 < DMODEL; k0 += 32) {
        __syncthreads();
        #pragma unroll
        for (int c = 0; c < 2; ++c) {
            const int base = c*4096 + wave*1024;
            const int byte = base + lane*16;
            const int row  = byte >> 6;
            const int ke   = (byte & 63) >> 1;
            gload16(A + (size_t)(m0+row)*DMODEL + k0 + ke, (char*)As + base);
            gload16(W + (size_t)(n0+row)*DMODEL + k0 + ke, (char*)Bs + base);
        }
        asm volatile("s_waitcnt vmcnt(0)" ::: "memory");
        __syncthreads();
        bf16x8 af[4], bfv[4];
        #pragma unroll
        for (int mf = 0; mf < 4; ++mf)
            af[mf] = *(const bf16x8*)((const char*)As + (wm*64 + mf*16 + l15)*64 + l4*16);
        #pragma unroll
        for (int nf = 0; nf < 4; ++nf)
            bfv[nf] = *(const bf16x8*)((const char*)Bs + (wn*64 + nf*16 + l15)*64 + l4*16);
        #pragma unroll
        for (int mf = 0; mf < 4; ++mf)
            #pragma unroll
            for (int nf = 0; nf < 4; ++nf)
                acc[mf][nf] = __builtin_amdgcn_mfma_f32_16x16x32_bf16(af[mf], bfv[nf], acc[mf][nf], 0, 0, 0);
    }

    float bv4[4];
    #pragma unroll
    for (int nf = 0; nf < 4; ++nf) bv4[nf] = bias[n0 + wn*64 + nf*16 + l15];

    const int rbase = m0 + wm*64 + l4*4;
    const int cbase = n0 + wn*64 + l15;

    if (mode == 1) {
        #pragma unroll
        for (int mf = 0; mf < 4; ++mf)
        #pragma unroll
        for (int nf = 0; nf < 4; ++nf) {
            const int col = cbase + nf*16;
            #pragma unroll
            for (int r = 0; r < 4; ++r) {
                const int row = rbase + mf*16 + r;
                outO[(size_t)row*DMODEL + col] = acc[mf][nf][r] + bv4[nf];
            }
        }
    } else if (which == 0) {
        const float qs = 0.08838834764831845f * 1.4426950408889634f;
        #pragma unroll
        for (int mf = 0; mf < 4; ++mf)
        #pragma unroll
        for (int nf = 0; nf < 4; ++nf) {
            const int col = cbase + nf*16;
            const int h = col >> 7, d = col & 127;
            #pragma unroll
            for (int r = 0; r < 4; ++r) {
                const int row = rbase + mf*16 + r;
                const int b = row >> 10, s = row & 1023;
                outQ[((size_t)(b*NH + h)*SS + s)*DK + d] = (bf16)((acc[mf][nf][r] + bv4[nf]) * qs);
            }
        }
    } else {
        float* dst = (which == 1) ? outK : outV;
        #pragma unroll
        for (int mf = 0; mf < 4; ++mf)
        #pragma unroll
        for (int nf = 0; nf < 4; ++nf) {
            const int col = cbase + nf*16;
            const int h = col >> 7, d = col & 127;
            #pragma unroll
            for (int r = 0; r < 4; ++r) {
                const int row = rbase + mf*16 + r;
                const int b = row >> 10, s = row & 1023;
                dst[((size_t)(b*NH + h)*LTOT + PASTLEN + s)*DK + d] = acc[mf][nf][r] + bv4[nf];
            }
        }
    }
}

// ---- K/V prep: past fp32 copy to d_out + bf16 swizzled tile blobs for attn ----
// K blob byte(r,d)  = r*256 + ((d*2) ^ ((r&7)<<4))      [64 rows x 128 d]
// V blob byte(d,r)  = d*128 + ((r*2) ^ ((d&7)<<4))      [transposed: 128 d-rows x 64 r]
__global__ __launch_bounds__(256) void kvprep_k(
    const float* __restrict__ pk, const float* __restrict__ pv,
    float* __restrict__ Kf, float* __restrict__ Vf,
    bf16* __restrict__ Kb, bf16* __restrict__ Vb)
{
    __shared__ float Vt_f[64*132];
    const int tid = threadIdx.x;
    const int tau = blockIdx.x, bh = blockIdx.y;
    const bool past = tau < 48;
    const size_t srcoff = past ? ((size_t)bh*PASTLEN + tau*64)*DK
                               : ((size_t)bh*LTOT    + tau*64)*DK;
    const float* srcK = (past ? pk : Kf) + srcoff;
    const float* srcV = (past ? pv : Vf) + srcoff;
    float* dstKf = Kf + ((size_t)bh*LTOT + tau*64)*DK;
    float* dstVf = Vf + ((size_t)bh*LTOT + tau*64)*DK;
    char* kblob = (char*)Kb + (((size_t)bh*KVTILES + tau) << 14);
    char* vblob = (char*)Vb + (((size_t)bh*KVTILES + tau) << 14);

    #pragma unroll
    for (int i = 0; i < 8; ++i) {
        const int f4 = i*256 + tid;        // 0..2047 float4s in the 64x128 tile
        const int r  = f4 >> 5;
        const int c8 = f4 & 31;            // float4 index within row
        float4 k4 = ((const float4*)srcK)[f4];
        float4 v4 = ((const float4*)srcV)[f4];
        if (past) {
            ((float4*)dstKf)[f4] = k4;
            ((float4*)dstVf)[f4] = v4;
        }
        bf16x4 kq; kq[0]=(bf16)k4.x; kq[1]=(bf16)k4.y; kq[2]=(bf16)k4.z; kq[3]=(bf16)k4.w;
        *(bf16x4*)(kblob + r*256 + ((c8*8) ^ ((r&7)<<4))) = kq;
        *(float4*)&Vt_f[r*132 + c8*4] = v4;
    }
    __syncthreads();
    const int d = tid >> 1, half = tid & 1;
    const int dx = (d & 7) << 4;
    #pragma unroll
    for (int j = 0; j < 4; ++j) {
        const int chunk = half*4 + j;      // 16B chunk = 8 consecutive kv rows
        bf16x8 o;
        #pragma unroll
        for (int e = 0; e < 8; ++e) o[e] = (bf16)Vt_f[(chunk*8 + e)*132 + d];
        *(bf16x8*)(vblob + d*128 + ((chunk*16) ^ dx)) = o;
    }
}

// ---- flash attention: 8 waves x 32q, split-KV=2, dbuf gload_lds staging ----
__global__ __launch_bounds__(512, 2) void attn_k(
    const bf16* __restrict__ Qb,
    const bf16* __restrict__ Kb, const bf16* __restrict__ Vb,
    bf16* __restrict__ Opart, float* __restrict__ Marr, float* __restrict__ Larr)
{
    __shared__ __align__(16) char KL[2][16384];
    __shared__ __align__(16) char VL[2][16384];
    __shared__ __align__(16) char PsL[8][4096];

    const int tid  = threadIdx.x;
    const int wave = tid >> 6, lane = tid & 63;
    const int l15 = lane & 15, l4 = lane >> 4;
    const int qt = blockIdx.x & 3;          // q tile of 256
    const int sp = blockIdx.x >> 2;         // kv split 0/1
    const int bh = blockIdx.y;
    const int qbase = qt*256 + wave*32;

    bf16x8 qf[2][4];
    #pragma unroll
    for (int qq = 0; qq < 2; ++qq) {
        const bf16* qptr = Qb + ((size_t)bh*SS + qbase + qq*16 + l15)*DK;
        #pragma unroll
        for (int ks = 0; ks < 4; ++ks)
            qf[qq][ks] = *(const bf16x8*)(qptr + ks*32 + l4*8);
    }

    const char* kblobs = (const char*)Kb + (((size_t)bh*KVTILES + sp*NT) << 14);
    const char* vblobs = (const char*)Vb + (((size_t)bh*KVTILES + sp*NT) << 14);
    char* myPs = PsL[wave];
    const int soff = wave*2048;             // this wave's 2KB staging slice

    float m_run[2][4], l_run[2][4];
    f32x4 oacc[2][8];
    #pragma unroll
    for (int qq = 0; qq < 2; ++qq) {
        #pragma unroll
        for (int r = 0; r < 4; ++r) { m_run[qq][r] = -1e30f; l_run[qq][r] = 0.f; }
        #pragma unroll
        for (int df = 0; df < 8; ++df) oacc[qq][df] = f32x4{0.f,0.f,0.f,0.f};
    }

    // prologue: stage tile 0 into buf 0
    #pragma unroll
    for (int c = 0; c < 2; ++c) {
        const int off = soff + c*1024;
        gload16(kblobs + off + lane*16, KL[0] + off);
        gload16(vblobs + off + lane*16, VL[0] + off);
    }

    for (int t = 0; t < NT; ++t) {
        const int cur = t & 1;
        if (t + 1 < NT) {
            const char* kb = kblobs + ((size_t)(t+1) << 14);
            const char* vb = vblobs + ((size_t)(t+1) << 14);
            #pragma unroll
            for (int c = 0; c < 2; ++c) {
                const int off = soff + c*1024;
                gload16(kb + off + lane*16, KL[cur^1] + off);
                gload16(vb + off + lane*16, VL[cur^1] + off);
            }
            asm volatile("s_waitcnt vmcnt(4)" ::: "memory");   // tile t's 4 loads done
        } else {
            asm volatile("s_waitcnt vmcnt(0)" ::: "memory");
        }
        __builtin_amdgcn_s_barrier();
        asm volatile("" ::: "memory");

        const char* Kc = KL[cur];
        const char* Vc = VL[cur];

        // ---- S = Q K^T (log2e units), K-frag shared across both q-subtiles ----
        f32x4 sa[2][4];
        #pragma unroll
        for (int qq = 0; qq < 2; ++qq)
            #pragma unroll
            for (int nf = 0; nf < 4; ++nf) sa[qq][nf] = f32x4{0.f,0.f,0.f,0.f};
        __builtin_amdgcn_s_setprio(1);
        #pragma unroll
        for (int nf = 0; nf < 4; ++nf) {
            const int krow = nf*16 + l15;
            const int rx = (krow & 7) << 4;
            #pragma unroll
            for (int ks = 0; ks < 4; ++ks) {
                bf16x8 kf = *(const bf16x8*)(Kc + krow*256 + ((ks*64 + l4*16) ^ rx));
                sa[0][nf] = __builtin_amdgcn_mfma_f32_16x16x32_bf16(qf[0][ks], kf, sa[0][nf], 0,0,0);
                sa[1][nf] = __builtin_amdgcn_mfma_f32_16x16x32_bf16(qf[1][ks], kf, sa[1][nf], 0,0,0);
            }
        }
        __builtin_amdgcn_s_setprio(0);

        // ---- online softmax (16-lane groups) + P -> LDS (swizzled) ----
        #pragma unroll
        for (int qq = 0; qq < 2; ++qq) {
            #pragma unroll
            for (int r = 0; r < 4; ++r) {
                float mt = fmaxf(fmaxf(sa[qq][0][r], sa[qq][1][r]),
                                 fmaxf(sa[qq][2][r], sa[qq][3][r]));
                #pragma unroll
                for (int off = 1; off < 16; off <<= 1) mt = fmaxf(mt, __shfl_xor(mt, off, 64));
                const float mn   = fmaxf(m_run[qq][r], mt);
                const float corr = exp2f(m_run[qq][r] - mn);
                m_run[qq][r] = mn;
                float sum = 0.f;
                #pragma unroll
                for (int nf = 0; nf < 4; ++nf) {
                    float p = exp2f(sa[qq][nf][r] - mn);
                    sa[qq][nf][r] = p;
                    sum += p;
                }
                #pragma unroll
                for (int off = 1; off < 16; off <<= 1) sum += __shfl_xor(sum, off, 64);
                l_run[qq][r] = l_run[qq][r]*corr + sum;
                #pragma unroll
                for (int df = 0; df < 8; ++df) oacc[qq][df][r] *= corr;
            }
            #pragma unroll
            for (int nf = 0; nf < 4; ++nf)
                #pragma unroll
                for (int r = 0; r < 4; ++r) {
                    const int row = qq*16 + l4*4 + r;
                    *(bf16*)(myPs + row*128 + (((nf*16 + l15)*2) ^ ((row&7)<<4))) = (bf16)sa[qq][nf][r];
                }
        }

        // ---- O += P V, V-frag shared across both q-subtiles ----
        bf16x8 pf[2][2];
        #pragma unroll
        for (int qq = 0; qq < 2; ++qq) {
            const int prow = qq*16 + l15;
            const int px = (prow & 7) << 4;
            #pragma unroll
            for (int ks2 = 0; ks2 < 2; ++ks2)
                pf[qq][ks2] = *(const bf16x8*)(myPs + prow*128 + ((ks2*64 + l4*16) ^ px));
        }
        __builtin_amdgcn_s_setprio(1);
        #pragma unroll
        for (int ks2 = 0; ks2 < 2; ++ks2) {
            #pragma unroll
            for (int df = 0; df < 8; ++df) {
                const int d = df*16 + l15;
                bf16x8 vf = *(const bf16x8*)(Vc + d*128 + ((ks2*64 + l4*16) ^ ((d&7)<<4)));
                oacc[0][df] = __builtin_amdgcn_mfma_f32_16x16x32_bf16(pf[0][ks2], vf, oacc[0][df], 0,0,0);
                oacc[1][df] = __builtin_amdgcn_mfma_f32_16x16x32_bf16(pf[1][ks2], vf, oacc[1][df], 0,0,0);
            }
        }
        __builtin_amdgcn_s_setprio(0);

        asm volatile("" ::: "memory");
        __builtin_amdgcn_s_barrier();
    }

    // ---- epilogue: unnormalized partial O (bf16) + per-row m,l ----
    bf16* op = Opart + ((size_t)sp*32 + bh)*SS*DK;
    #pragma unroll
    for (int qq = 0; qq < 2; ++qq)
        #pragma unroll
        for (int df = 0; df < 8; ++df)
            #pragma unroll
            for (int r = 0; r < 4; ++r) {
                const int q = qbase + qq*16 + l4*4 + r;
                op[(size_t)q*DK + df*16 + l15] = (bf16)oacc[qq][df][r];
            }
    if (l15 == 0) {
        #pragma unroll
        for (int qq = 0; qq < 2; ++qq)
            #pragma unroll
            for (int r = 0; r < 4; ++r) {
                const int q = qbase + qq*16 + l4*4 + r;
                Marr[(size_t)sp*32768 + bh*SS + q] = m_run[qq][r];
                Larr[(size_t)sp*32768 + bh*SS + q] = l_run[qq][r];
            }
    }
}

// ---- combine the two KV splits -> Ob bf16 [B*S][DMODEL] ----
__global__ __launch_bounds__(256) void combine_k(
    const bf16* __restrict__ Opart, const float* __restrict__ Marr,
    const float* __restrict__ Larr, bf16* __restrict__ Ob)
{
    const int gid = blockIdx.x*256 + threadIdx.x;   // 32768 rows x 16 chunks
    const int row = gid >> 4;                       // bh*1024 + q
    const int c8  = gid & 15;
    const int bh = row >> 10, q = row & 1023;
    const float m0 = Marr[row], m1 = Marr[32768 + row];
    const float l0 = Larr[row], l1 = Larr[32768 + row];
    const float M = fmaxf(m0, m1);
    float a0 = exp2f(m0 - M), a1 = exp2f(m1 - M);
    const float inv = 1.f / (l0*a0 + l1*a1);
    a0 *= inv; a1 *= inv;
    bf16x8 p0 = *(const bf16x8*)(Opart + (size_t)row*DK + c8*8);
    bf16x8 p1 = *(const bf16x8*)(Opart + 4194304 + (size_t)row*DK + c8*8);
    const int b = bh >> 4, h = bh & 15;
    bf16x8 o;
    #pragma unroll
    for (int e = 0; e < 8; ++e) o[e] = (bf16)((float)p0[e]*a0 + (float)p1[e]*a1);
    *(bf16x8*)(Ob + ((size_t)(b*SS + q))*DMODEL + h*DK + c8*8) = o;
}

extern "C" void kernel_launch(void* const* d_in, const int* in_sizes, int n_in,
                              void* d_out, int out_size, void* d_ws, size_t ws_size,
                              hipStream_t stream) {
    const float* x  = (const float*)d_in[0];
    const float* pk = (const float*)d_in[1];
    const float* pv = (const float*)d_in[2];
    const float* Wq = (const float*)d_in[3];
    const float* bq = (const float*)d_in[4];
    const float* Wk = (const float*)d_in[5];
    const float* bk = (const float*)d_in[6];
    const float* Wv = (const float*)d_in[7];
    const float* bv = (const float*)d_in[8];
    const float* Wo = (const float*)d_in[9];
    const float* bo = (const float*)d_in[10];

    float* out  = (float*)d_out;                 // [B,S,DMODEL]
    float* Kout = out + 4194304;                 // [B,H,4096,128] fp32
    float* Vout = out + 20971520;

    char* ws = (char*)d_ws;
    bf16* xb    = (bf16*)(ws);
    bf16* Wqb   = (bf16*)(ws + (size_t)8*1024*1024);
    bf16* Wkb   = (bf16*)(ws + (size_t)16*1024*1024);
    bf16* Wvb   = (bf16*)(ws + (size_t)24*1024*1024);
    bf16* Wob   = (bf16*)(ws + (size_t)32*1024*1024);
    bf16* Qb    = (bf16*)(ws + (size_t)40*1024*1024);
    bf16* Ob    = (bf16*)(ws + (size_t)48*1024*1024);
    bf16* Kb    = (bf16*)(ws + (size_t)56*1024*1024);   // 32 MB swizzled tiles
    bf16* Vb    = (bf16*)(ws + (size_t)88*1024*1024);   // 32 MB swizzled tiles
    // recycled after QKV GEMM (xb/Wqb/Wkb/Wvb dead):
    bf16*  Opart = (bf16*)(ws);                          // 16.78 MB
    float* Marr  = (float*)(ws + (size_t)24*1024*1024);  // 256 KB
    float* Larr  = (float*)(ws + (size_t)25*1024*1024);  // 256 KB

    // 1) fp32 -> bf16 converts
    cvt5_k<<<dim3(1024, 5), 256, 0, stream>>>(x, Wq, Wk, Wv, Wo,
                                              xb, Wqb, Wkb, Wvb, Wob, 524288);
    // 2) fused QKV projection (writes Qb bf16 + new K/V fp32 rows)
    gemm_bt<<<dim3(16, 48), 256, 0, stream>>>(xb, Wqb, Wkb, Wvb, bq, bk, bv,
                                              Qb, Kout, Vout, nullptr, 0);
    // 3) K/V prep: past fp32 copy + bf16 swizzled tile blobs (all 4096 rows)
    kvprep_k<<<dim3(64, 32), 256, 0, stream>>>(pk, pv, Kout, Vout, Kb, Vb);
    // 4) flash attention (split-KV = 2)
    attn_k<<<dim3(8, 32), 512, 0, stream>>>(Qb, Kb, Vb, Opart, Marr, Larr);
    // 5) combine splits
    combine_k<<<2048, 256, 0, stream>>>(Opart, Marr, Larr, Ob);
    // 6) output projection
    gemm_bt<<<dim3(16, 16), 256, 0, stream>>>(Ob, Wob, nullptr, nullptr, bo, nullptr, nullptr,
                                              nullptr, nullptr, nullptr, out, 1);
}